// Round 13
// baseline (241.618 us; speedup 1.0000x reference)
//
#include <hip/hip_runtime.h>
#include <hip/hip_bf16.h>

// Problem dims (fixed by reference)
//   B=128, T=256, D_MODEL=128, D_INNER=256, D_STATE=16, D_CONV=4, DT_RANK=8
// I/O dtype: float32. MFMA bf16 for in_proj/x_proj/fused-tail. R24:
//  - R12 post-mortem: front_k fusion -22.1us, absmax restored. Ledger says
//    bottom-up kernel estimates (~110us) << measured 225us -> the residual
//    lives in inter-launch gaps (~10-20us each). Every fusion that removed a
//    launch gained MORE than the deleted kernel's compute (R3 -43, R4 -35,
//    R12 -22).
//  - R24: 4 -> 3 launches. prep_all absorbed into front_k:
//    * W-fragments loaded fp32 + converted in-reg (same f2s rounding ->
//      identical numerics); xpw rows>=40 zero-masked; x_proj's all-zero
//      j=3 n-tile skipped (-8 MFMA/wave).
//    * A-tile staged from fp32 x directly; rows t>=t0 also write the out1
//      x_skip copy from the same loads. xb round-trip deleted.
//    * G computed by blocks 0..383 as a prologue (same math, same bits).
//    All extra reads L2-resident (x 16.8MB, ipw 256KB).
//  - scan12 FROZEN; od_k unchanged (R8 form).
// Outputs: h (128,128,128) then x_skip (128,256,128), fp32, concatenated.

typedef __attribute__((ext_vector_type(8))) short bf16x8;
typedef __attribute__((ext_vector_type(4))) short bf16x4;
typedef __attribute__((ext_vector_type(4))) float f32x4;
using bf16 = __hip_bfloat16;

static __device__ __forceinline__ short f2s(float v) {
  union { bf16 b; short s; } u; u.b = (bf16)v; return u.s;
}
static __device__ __forceinline__ float s2f(short s) {
  union { short s; bf16 b; } u; u.s = s; return (float)u.b;
}
// load 8 consecutive fp32 and convert to bf16x8 (same rounding as prep_all)
static __device__ __forceinline__ bf16x8 ld8f(const float* __restrict__ p) {
  f32x4 a = *(const f32x4*)p;
  f32x4 b = *(const f32x4*)(p + 4);
  bf16x8 r;
  r[0] = f2s(a[0]); r[1] = f2s(a[1]); r[2] = f2s(a[2]); r[3] = f2s(a[3]);
  r[4] = f2s(b[0]); r[5] = f2s(b[1]); r[6] = f2s(b[2]); r[7] = f2s(b[3]);
  return r;
}

// packed stream index: (b, d, t) -> [b][g=d>>5][c=t>>3][dl=d&31][tt=t&7]
static __device__ __forceinline__ size_t pidx(int b, int d, int t) {
  return ((((size_t)b * 8 + (d >> 5)) * 32 + (t >> 3)) * 32 + (d & 31)) * 8 + (t & 7);
}

// ---------------------------------------------------------------------------
// front_k: fused (weight-cvt + x-cvt + x_skip copy + G-prep) + in_proj +
// depthwise conv/silu + x_proj + delta.
// Block = (b, 64-t quarter), 512 blocks x 256 thr (4 waves), ~75KB LDS
// -> 2 blocks/CU, grid fully co-resident.
//  G-prep:  blocks 0..383 compute G_k[co,:] first (wave-uniform dwn loads).
//  stage:   A-tile = x rows t0-16..t0+63 fp32 -> bf16 LDS (0-fill t<0);
//           rows >= t0 also copied to out1 (x_skip).
//  xc GEMM: M=80 N=256 K=128; W-frags ld8f(ipw). C-frags -> XC[t][d].
//  z GEMM:  M=64 N=256 K=128, nt-loop; W-frags ld8f(ipw rows 256+); silu ->
//           LT transpose -> packed zP.
//  conv:    thread (wave=16t, lane=d) x 4 dtiles from XC (+3-row halo);
//           regs -> xcP packed; XC write-back after barrier.
//  x_proj:  N=48 (j=0..2; j=2 rows>=40 zero-masked; j=3 all-zero skipped),
//           K=256 from XC; dt->DTL, B/C -> SBC fp32.
//  delta:   softplus(dt . dtw + dtb) -> dP packed.
// ---------------------------------------------------------------------------
__global__ __launch_bounds__(256, 2) void front_k(const float* __restrict__ x,
                                                  const float* __restrict__ ipw,
                                                  const float* __restrict__ xpw,
                                                  const float* __restrict__ dwn,
                                                  const float* __restrict__ opw,
                                                  const float* __restrict__ cw,
                                                  const float* __restrict__ cb,
                                                  const float* __restrict__ dtw,
                                                  const float* __restrict__ dtb,
                                                  short* __restrict__ xcP,
                                                  short* __restrict__ dP,
                                                  short* __restrict__ zP,
                                                  float* __restrict__ SBC,
                                                  float* __restrict__ out1,
                                                  short* __restrict__ G) {
  const int b  = blockIdx.x >> 2;
  const int t0 = (blockIdx.x & 3) * 64;
  const int w    = threadIdx.x >> 6;    // wave id (0..3)
  const int lane = threadIdx.x & 63;
  const int r16  = lane & 15;
  const int quad = lane >> 4;
  __shared__ short AL[80][136];         // A-tile [row=t-(t0-16)][k], pad 8
  __shared__ short XC[80][264];         // xc pre/post conv [row][d], pad 8
  __shared__ short LT[64][72];          // z transpose tile
  __shared__ float DTL[64][8];          // dt cols per t-local
  // ---- G-prep (blocks 0..383): G_k[co,e] = sum_dm dwn[co,dm,k]*opw[dm,e]
  if (blockIdx.x < 384) {
    const int k  = blockIdx.x >> 7;
    const int co = blockIdx.x & 127;
    const int e  = threadIdx.x;
    float acc = 0.f;
#pragma unroll 4
    for (int dm = 0; dm < 128; ++dm) {
      acc += dwn[(co * 128 + dm) * 3 + k] * opw[dm * 256 + e];
    }
    G[(size_t)(k * 128 + co) * 256 + e] = f2s(acc);
  }
  // ---- stage A-tile from fp32 x (+ x_skip copy for rows >= t0) ----
  for (int c = threadIdx.x; c < 1280; c += 256) {
    const int row = c >> 4;
    const int col = (c & 15) * 8;
    const int t = t0 - 16 + row;
    bf16x8 v = {};
    if (t >= 0) {
      const float* src = x + ((size_t)(b * 256 + t)) * 128 + col;
      f32x4 f0 = *(const f32x4*)src;
      f32x4 f1 = *(const f32x4*)(src + 4);
      v[0] = f2s(f0[0]); v[1] = f2s(f0[1]); v[2] = f2s(f0[2]); v[3] = f2s(f0[3]);
      v[4] = f2s(f1[0]); v[5] = f2s(f1[1]); v[6] = f2s(f1[2]); v[7] = f2s(f1[3]);
      if (row >= 16) {                 // t in [t0, t0+64): x_skip passthrough
        float* dst = out1 + ((size_t)(b * 256 + t)) * 128 + col;
        *(f32x4*)dst = f0;
        *(f32x4*)(dst + 4) = f1;
      }
    }
    *(bf16x8*)(&AL[row][col]) = v;
  }
  __syncthreads();
  // ---- xc GEMM: wave w -> cols w*64..w*64+63, M=80 ----
  {
    f32x4 acc[5][4] = {};
#pragma unroll
    for (int ks = 0; ks < 4; ++ks) {
      const int k0 = ks * 32;
      bf16x8 wf[4];
#pragma unroll
      for (int j = 0; j < 4; ++j)
        wf[j] = ld8f(ipw + (size_t)(w * 64 + j * 16 + r16) * 128 + quad * 8 + k0);
#pragma unroll
      for (int mt = 0; mt < 5; ++mt) {
        bf16x8 a = *(const bf16x8*)(&AL[mt * 16 + r16][quad * 8 + k0]);
#pragma unroll
        for (int j = 0; j < 4; ++j)
          acc[mt][j] = __builtin_amdgcn_mfma_f32_16x16x32_bf16(a, wf[j],
                                                               acc[mt][j], 0, 0, 0);
      }
    }
#pragma unroll
    for (int mt = 0; mt < 5; ++mt)
#pragma unroll
      for (int j = 0; j < 4; ++j)
#pragma unroll
        for (int r = 0; r < 4; ++r)
          XC[mt * 16 + quad * 4 + r][w * 64 + j * 16 + r16] = f2s(acc[mt][j][r]);
  }
  // ---- z GEMM + silu -> zP packed (LT transpose per nt) ----
  for (int nt = 0; nt < 4; ++nt) {
    f32x4 accz[4] = {};
#pragma unroll
    for (int ks = 0; ks < 4; ++ks) {
      const int k0 = ks * 32;
      bf16x8 a = *(const bf16x8*)(&AL[16 + w * 16 + r16][quad * 8 + k0]);
#pragma unroll
      for (int j = 0; j < 4; ++j) {
        bf16x8 wf = ld8f(ipw +
                 (size_t)(256 + nt * 64 + j * 16 + r16) * 128 + quad * 8 + k0);
        accz[j] = __builtin_amdgcn_mfma_f32_16x16x32_bf16(a, wf, accz[j], 0, 0, 0);
      }
    }
    __syncthreads();                    // prior LT reads done (and XC epilogue)
#pragma unroll
    for (int j = 0; j < 4; ++j)
#pragma unroll
      for (int r = 0; r < 4; ++r) {
        float v = accz[j][r];
        LT[j * 16 + r16][w * 16 + quad * 4 + r] = f2s(v / (1.f + __expf(-v)));
      }
    __syncthreads();
#pragma unroll
    for (int it = 0; it < 2; ++it) {
      const int dw = (threadIdx.x >> 3) + it * 32;
      const int tc = (threadIdx.x & 7) * 8;
      bf16x8 v = *(const bf16x8*)(&LT[dw][tc]);
      *(bf16x8*)(zP + pidx(b, nt * 64 + dw, t0 + tc)) = v;
    }
  }
  __syncthreads();
  // ---- conv + silu: thread (wave=16t, lane=d) x 4 dtiles ----
  bf16x8 cv[4][2];
#pragma unroll
  for (int dt_ = 0; dt_ < 4; ++dt_) {
    const int d = dt_ * 64 + lane;
    const float w0 = cw[d * 4], w1 = cw[d * 4 + 1];
    const float w2 = cw[d * 4 + 2], w3 = cw[d * 4 + 3];
    const float bias = cb[d];
    const int rb_ = 16 + w * 16;        // XC row of first output t
    float p0 = s2f(XC[rb_ - 3][d]);
    float p1 = s2f(XC[rb_ - 2][d]);
    float p2 = s2f(XC[rb_ - 1][d]);
#pragma unroll
    for (int i = 0; i < 16; ++i) {
      const float cur = s2f(XC[rb_ + i][d]);
      const float a = bias + p0 * w0 + p1 * w1 + p2 * w2 + cur * w3;
      const short s = f2s(a / (1.f + __expf(-a)));
      cv[dt_][i >> 3][i & 7] = s;
      p0 = p1; p1 = p2; p2 = cur;
    }
    *(bf16x8*)(xcP + pidx(b, d, t0 + w * 16))     = cv[dt_][0];
    *(bf16x8*)(xcP + pidx(b, d, t0 + w * 16 + 8)) = cv[dt_][1];
  }
  __syncthreads();
#pragma unroll
  for (int dt_ = 0; dt_ < 4; ++dt_) {
    const int d = dt_ * 64 + lane;
#pragma unroll
    for (int i = 0; i < 16; ++i)
      XC[16 + w * 16 + i][d] = cv[dt_][i >> 3][i & 7];
  }
  __syncthreads();
  // ---- x_proj MFMA: wave w = m-tile w (16 t), N=48 (40 used), K=256 ----
  {
    f32x4 ax[3] = {};
#pragma unroll
    for (int ks = 0; ks < 8; ++ks) {
      const int k0 = ks * 32;
      bf16x8 a = *(const bf16x8*)(&XC[16 + w * 16 + r16][quad * 8 + k0]);
#pragma unroll
      for (int j = 0; j < 3; ++j) {
        const int wr = j * 16 + r16;
        bf16x8 wf = {};
        if (wr < 40) wf = ld8f(xpw + (size_t)wr * 256 + quad * 8 + k0);
        ax[j] = __builtin_amdgcn_mfma_f32_16x16x32_bf16(a, wf, ax[j], 0, 0, 0);
      }
    }
#pragma unroll
    for (int j = 0; j < 3; ++j) {
      const int col = j * 16 + r16;
#pragma unroll
      for (int r = 0; r < 4; ++r) {
        const int tl = w * 16 + quad * 4 + r;
        if (col < 8) {
          DTL[tl][col] = ax[j][r];
        } else if (col < 40) {
          SBC[((size_t)b * 256 + t0 + tl) * 32 + (col - 8)] = ax[j][r];
        }
      }
    }
  }
  __syncthreads();
  // ---- delta = softplus(dt . dtw + dtb) -> dP packed ----
#pragma unroll
  for (int dt_ = 0; dt_ < 4; ++dt_) {
    const int d = dt_ * 64 + lane;
    float wd[8];
#pragma unroll
    for (int j = 0; j < 8; ++j) wd[j] = dtw[d * 8 + j];
    const float bd = dtb[d];
    bf16x8 dv0, dv1;
#pragma unroll
    for (int i = 0; i < 16; ++i) {
      const int tl = w * 16 + i;
      const f32x4 p0 = *(const f32x4*)(&DTL[tl][0]);
      const f32x4 p1 = *(const f32x4*)(&DTL[tl][4]);
      float acc = bd;
#pragma unroll
      for (int j = 0; j < 4; ++j) acc += p0[j] * wd[j] + p1[j] * wd[4 + j];
      const float delta = (acc > 20.f) ? acc : __logf(1.f + __expf(acc));
      const short s = f2s(delta);
      if (i < 8) dv0[i] = s; else dv1[i - 8] = s;
    }
    *(bf16x8*)(dP + pidx(b, d, t0 + w * 16))     = dv0;
    *(bf16x8*)(dP + pidx(b, d, t0 + w * 16 + 8)) = dv1;
  }
}

// ---------------------------------------------------------------------------
// scan12 (FROZEN): R8 skeleton + packed u/d/z reads. Block = (b, group of 32
// d), 128 thr = 32 d x 4 lanes; lane owns 4 of 16 states, serial T=256.
// u/d/z packed streams: one contiguous 256B segment per wave-load. uu/dd/zz
// [4] named rotation, 4-phase unrolled; chunk c+4 issued right after chunk c
// consumed. S (B/C fp32) 2-phase LDS, 32KB. y scatter store (q==0).
// ---------------------------------------------------------------------------
#define LDS_S(SB, CH) do {                                                   \
    _Pragma("unroll")                                                        \
    for (int j_ = 0; j_ < 8; ++j_) {                                         \
      SBr[SB][j_] = *(const f32x4*)(&S[(CH) * 8 + j_][q * 4]);               \
      SCr[SB][j_] = *(const f32x4*)(&S[(CH) * 8 + j_][16 + q * 4]);          \
    }                                                                        \
  } while (0)

#define LDG(GB, CH) do {                                                     \
    if ((CH) < 32) {                                                         \
      uu[GB] = *(const bf16x8*)(xcP + pb + (size_t)(CH) * 256);              \
      dd[GB] = *(const bf16x8*)(dP + pb + (size_t)(CH) * 256);               \
      if (q == 0) zz[GB] = *(const bf16x8*)(zP + pb + (size_t)(CH) * 256);   \
    }                                                                        \
  } while (0)

#define CHUNK(GB, SB, CH) do {                                               \
    _Pragma("unroll")                                                        \
    for (int tt_ = 0; tt_ < 8; ++tt_) {                                      \
      const int t_ = (CH) * 8 + tt_;                                         \
      const float delta_ = s2f(dd[GB][tt_]);                                 \
      const float u_ = s2f(uu[GB][tt_]);                                     \
      const float du_ = delta_ * u_;                                         \
      const f32x4 Bq_ = SBr[SB][tt_];                                        \
      const f32x4 Cq_ = SCr[SB][tt_];                                        \
      float yt_ = 0.f;                                                       \
      _Pragma("unroll")                                                      \
      for (int n_ = 0; n_ < 4; ++n_) {                                       \
        const float dA_ = __builtin_amdgcn_exp2f(delta_ * A2[n_]);           \
        h[n_] = dA_ * h[n_] + du_ * Bq_[n_];                                 \
        yt_ += h[n_] * Cq_[n_];                                              \
      }                                                                      \
      yt_ += __shfl_xor(yt_, 1);                                             \
      yt_ += __shfl_xor(yt_, 2);                                             \
      if (q == 0)                                                            \
        yb[(rb + t_) * 256 + d] = f2s((yt_ + u_ * Dv) * s2f(zz[GB][tt_]));   \
    }                                                                        \
  } while (0)

__global__ __launch_bounds__(128, 2) void scan12(const float* __restrict__ SBC,
                                                 const short* __restrict__ xcP,
                                                 const short* __restrict__ dP,
                                                 const short* __restrict__ zP,
                                                 const float* __restrict__ alog,
                                                 const float* __restrict__ Dp,
                                                 short* __restrict__ yb) {
  const int g = blockIdx.x & 7;
  const int b = blockIdx.x >> 3;
  const int q = threadIdx.x & 3;
  const int dl = threadIdx.x >> 2;            // 0..31 within group
  const int d = g * 32 + dl;
  const size_t rb = (size_t)b * 256;
  __shared__ float S[256][32];                // B(16)|C(16) fp32 per t, 32 KB
  for (int i = threadIdx.x; i < 2048; i += 128) {
    *(f32x4*)(&S[i >> 3][(i & 7) * 4]) =
        *(const f32x4*)(SBC + (size_t)b * 8192 + i * 4);
  }
  float A2[4];
#pragma unroll
  for (int n = 0; n < 4; ++n)
    A2[n] = -__expf(alog[d * 16 + q * 4 + n]) * 1.44269504089f;
  const float Dv = Dp[d];
  float h[4] = {0.f, 0.f, 0.f, 0.f};
  // packed per-lane base: [b][g][c=0][dl][0]
  const size_t pb = (((size_t)b * 8 + g) * 32) * 256 + (size_t)dl * 8;
  f32x4 SBr[2][8], SCr[2][8];
  bf16x8 uu[4], dd[4];
  bf16x8 zz[4] = {};
  // 4-deep global prologue (issues before the LDS-fill barrier)
  LDG(0, 0); LDG(1, 1); LDG(2, 2); LDG(3, 3);
  __syncthreads();
  LDS_S(0, 0);
  for (int c = 0; c < 32; c += 4) {
    LDS_S(1, c + 1);
    CHUNK(0, 0, c);
    LDG(0, c + 4);
    LDS_S(0, c + 2);
    CHUNK(1, 1, c + 1);
    LDG(1, c + 5);
    LDS_S(1, c + 3);
    CHUNK(2, 0, c + 2);
    LDG(2, c + 6);
    if (c + 4 < 32) LDS_S(0, c + 4);
    CHUNK(3, 1, c + 3);
    LDG(3, c + 7);
  }
}

// ---------------------------------------------------------------------------
// od_k (R8 form): fused out_proj + strided down-conv + bias + LayerNorm.
//   pre[b,to,co] = sum_k yb[b,2to+k-1,:] . G_k[co,:] + db[co]; out = LN(pre).
// Grid 256 x 256 thr (4 waves x 16 m-rows); K=768 via 3 row-shifted K=256
// segments; G L2-resident; LN via 16-lane shfl_xor.
// ---------------------------------------------------------------------------
__global__ __launch_bounds__(256) void od_k(const short* __restrict__ yb,
                                            const short* __restrict__ G,
                                            const float* __restrict__ db,
                                            const float* __restrict__ lng,
                                            const float* __restrict__ lnb,
                                            float* __restrict__ out) {
  const int wave = threadIdx.x >> 6;
  const int lane = threadIdx.x & 63;
  const int r16  = lane & 15;
  const int quad = lane >> 4;
  const int m_base = blockIdx.x * 64 + wave * 16;
  const int ma = m_base + r16;
  const int ba = ma >> 7, toa = ma & 127;
  f32x4 acc[8] = {};
  const bf16x8 az = {};
#pragma unroll
  for (int k = 0; k < 3; ++k) {
    const int tp = 2 * toa + k - 1;
    const bool valid = (tp >= 0) && (tp < 256);
    const int tpc = tp < 0 ? 0 : (tp > 255 ? 255 : tp);
    const short* Ap = yb + (size_t)(ba * 256 + tpc) * 256 + quad * 8;
    const short* Gp = G + (size_t)(k * 128 + r16) * 256 + quad * 8;
#pragma unroll
    for (int k0 = 0; k0 < 256; k0 += 32) {
      bf16x8 a = *(const bf16x8*)(Ap + k0);
      a = valid ? a : az;
#pragma unroll
      for (int j = 0; j < 8; ++j) {
        bf16x8 g = *(const bf16x8*)(Gp + (size_t)j * 16 * 256 + k0);
        acc[j] = __builtin_amdgcn_mfma_f32_16x16x32_bf16(a, g, acc[j], 0, 0, 0);
      }
    }
  }
  float dbv[8], g8[8], be8[8];
#pragma unroll
  for (int j = 0; j < 8; ++j) {
    const int col = j * 16 + r16;
    dbv[j] = db[col]; g8[j] = lng[col]; be8[j] = lnb[col];
  }
#pragma unroll
  for (int r = 0; r < 4; ++r) {
    float v[8];
    float s = 0.f;
#pragma unroll
    for (int j = 0; j < 8; ++j) { v[j] = acc[j][r] + dbv[j]; s += v[j]; }
    s += __shfl_xor(s, 1); s += __shfl_xor(s, 2);
    s += __shfl_xor(s, 4); s += __shfl_xor(s, 8);
    const float mu = s * (1.0f / 128.0f);
    float vs = 0.f;
#pragma unroll
    for (int j = 0; j < 8; ++j) { const float dd = v[j] - mu; vs += dd * dd; }
    vs += __shfl_xor(vs, 1); vs += __shfl_xor(vs, 2);
    vs += __shfl_xor(vs, 4); vs += __shfl_xor(vs, 8);
    const float rstd = rsqrtf(vs * (1.0f / 128.0f) + 1e-5f);
    const int rowm = m_base + quad * 4 + r;
#pragma unroll
    for (int j = 0; j < 8; ++j) {
      out[(size_t)rowm * 128 + j * 16 + r16] = (v[j] - mu) * rstd * g8[j] + be8[j];
    }
  }
}

// ---------------------------------------------------------------------------
// Workspace layout (bytes), peak 92,471,296 == proven-safe bound:
//   [0,16M)      yb bf16 (scan->od_k)
//   [16M,32M)    xcP bf16 packed (front_k->scan)
//   [32M,48M)    zP bf16 packed (front_k->scan)
//   [48M,64M)    dP bf16 packed (front_k->scan)
//   [64M,68.2M)  SBC fp32 4MB (front_k->scan)
//   [68.2M..71.5M) G bf16 196,608B (front_k->od_k)
// out1 (x_skip) written once by front_k; od_k writes out0 LAST.
// ---------------------------------------------------------------------------
static const size_t O_YB    = 0;
static const size_t O_XCP   = 16777216;
static const size_t O_ZP    = 33554432;
static const size_t O_DP    = 50331648;
static const size_t O_SBC   = 67108864;     // 4,194,304 B
static const size_t O_G     = 71303168;     // 196,608 B

extern "C" void kernel_launch(void* const* d_in, const int* in_sizes, int n_in,
                              void* d_out, int out_size, void* d_ws, size_t ws_size,
                              hipStream_t stream) {
  const float* x    = (const float*)d_in[0];
  const float* ipw  = (const float*)d_in[1];
  const float* cw   = (const float*)d_in[2];
  const float* cb   = (const float*)d_in[3];
  const float* xpw  = (const float*)d_in[4];
  const float* dtw  = (const float*)d_in[5];
  const float* dtb  = (const float*)d_in[6];
  const float* alog = (const float*)d_in[7];
  const float* Dp   = (const float*)d_in[8];
  const float* opw  = (const float*)d_in[9];
  const float* dw   = (const float*)d_in[10];
  const float* db   = (const float*)d_in[11];
  const float* lng  = (const float*)d_in[12];
  const float* lnb  = (const float*)d_in[13];

  char*  ws     = (char*)d_ws;
  short* yb     = (short*)(ws + O_YB);
  short* xcP    = (short*)(ws + O_XCP);
  short* zP     = (short*)(ws + O_ZP);
  short* dP     = (short*)(ws + O_DP);
  float* SBC    = (float*)(ws + O_SBC);
  short* G      = (short*)(ws + O_G);
  float* out    = (float*)d_out;
  float* out1   = out + 2097152;

  // 1. fused prep + in_proj + conv/silu + x_proj + delta (+ out1, + G)
  front_k<<<512, 256, 0, stream>>>(x, ipw, xpw, dw, opw, cw, cb, dtw, dtb,
                                   xcP, dP, zP, SBC, out1, G);
  // 2. state-parallel scan (FROZEN) -> yb
  scan12<<<1024, 128, 0, stream>>>(SBC, xcP, dP, zP, alog, Dp, yb);
  // 3. fused out_proj + down-conv + bias + LayerNorm -> output 0
  od_k<<<256, 256, 0, stream>>>(yb, G, db, lng, lnb, out);
}

// Round 16
// 219.240 us; speedup vs baseline: 1.1021x; 1.1021x over previous
//
#include <hip/hip_runtime.h>
#include <hip/hip_bf16.h>

// Problem dims (fixed by reference)
//   B=128, T=256, D_MODEL=128, D_INNER=256, D_STATE=16, D_CONV=4, DT_RANK=8
// I/O dtype: float32. MFMA bf16 for in_proj/x_proj/fused-tail. R27:
//  - R14/R15 post-mortem: in-kernel cross-block weight handshake failed twice
//    (R14 grid.sync -> stale lines, absmax 0.116; R15 atomic spin -> container
//    hang). ABANDONED: stream-ordered launches are the only ordering
//    primitive that has worked. No atomics, no cooperative launch.
//  - R27 safe reconstruction (every path bit-identical to a PASSING round):
//    * prep_w: tiny 320-block kernel, ONLY ipw->ipwb + xpw->wxb (R12 branch).
//    * front_k: R12 GEMM internals (bf16 weights) + R13's verified
//      A-from-fp32-x staging + out1 x_skip fusion. cvt_x round-trip stays
//      deleted. No G, no handshake.
//    * G-prep rides in scan12's grid (blocks 1024..1791); G consumed only by
//      od_k (next launch) -> ordering free and safe.
//  - scan12 FROZEN; od_k unchanged (R8 form).
// Outputs: h (128,128,128) then x_skip (128,256,128), fp32, concatenated.

typedef __attribute__((ext_vector_type(8))) short bf16x8;
typedef __attribute__((ext_vector_type(4))) short bf16x4;
typedef __attribute__((ext_vector_type(4))) float f32x4;
using bf16 = __hip_bfloat16;

static __device__ __forceinline__ short f2s(float v) {
  union { bf16 b; short s; } u; u.b = (bf16)v; return u.s;
}
static __device__ __forceinline__ float s2f(short s) {
  union { short s; bf16 b; } u; u.s = s; return (float)u.b;
}

// packed stream index: (b, d, t) -> [b][g=d>>5][c=t>>3][dl=d&31][tt=t&7]
static __device__ __forceinline__ size_t pidx(int b, int d, int t) {
  return ((((size_t)b * 8 + (d >> 5)) * 32 + (t >> 3)) * 32 + (d & 31)) * 8 + (t & 7);
}

// ---------------------------------------------------------------------------
// prep_w: ipw(512x128)->bf16 ipwb; x_proj_w -> wxb (64x256 bf16, rows 40..63
// zero; staged in out0 -- safe: od_k writes out0 LAST, after wxb consumed).
// 320 blocks x 256 thr. (R12 prep_all branch, verbatim.)
// ---------------------------------------------------------------------------
__global__ __launch_bounds__(256) void prep_w(const float* __restrict__ ipw,
                                              const float* __restrict__ xpw,
                                              short* __restrict__ ipwb,
                                              short* __restrict__ wxb) {
  int idx = blockIdx.x * 256 + threadIdx.x;   // 0 .. 81919
  if (idx < 65536) {
    ipwb[idx] = f2s(ipw[idx]);
  } else {
    int j = idx - 65536;          // n*256 + k
    int n = j >> 8;
    wxb[j] = (n < 40) ? f2s(xpw[j]) : (short)0;
  }
}

// ---------------------------------------------------------------------------
// front_k: fused in_proj + depthwise conv/silu + x_proj + delta, with A-tile
// staged straight from fp32 x (+ out1 x_skip copy). bf16 weights from
// ipwb/wxb (prep_w, prior launch). Block = (b, 64-t quarter), 512 blocks x
// 256 thr (4 waves), 75,264B LDS -> 2 blocks/CU.
// ---------------------------------------------------------------------------
__global__ __launch_bounds__(256, 2) void front_k(const float* __restrict__ x,
                                                  const short* __restrict__ ipwb,
                                                  const short* __restrict__ wxb,
                                                  const float* __restrict__ cw,
                                                  const float* __restrict__ cb,
                                                  const float* __restrict__ dtw,
                                                  const float* __restrict__ dtb,
                                                  short* __restrict__ xcP,
                                                  short* __restrict__ dP,
                                                  short* __restrict__ zP,
                                                  float* __restrict__ SBC,
                                                  float* __restrict__ out1) {
  const int b  = blockIdx.x >> 2;
  const int t0 = (blockIdx.x & 3) * 64;
  const int w    = threadIdx.x >> 6;    // wave id (0..3)
  const int lane = threadIdx.x & 63;
  const int r16  = lane & 15;
  const int quad = lane >> 4;
  __shared__ short AL[80][136];         // A-tile [row=t-(t0-16)][k], pad 8
  __shared__ short XC[80][264];         // xc pre/post conv [row][d], pad 8
  __shared__ short LT[64][72];          // z transpose tile
  __shared__ float DTL[64][8];          // dt cols per t-local
  // ---- stage A-tile from fp32 x (+ x_skip copy for rows >= t0) ----
  for (int c = threadIdx.x; c < 1280; c += 256) {
    const int row = c >> 4;
    const int col = (c & 15) * 8;
    const int t = t0 - 16 + row;
    bf16x8 v = {};
    if (t >= 0) {
      const float* src = x + ((size_t)(b * 256 + t)) * 128 + col;
      f32x4 f0 = *(const f32x4*)src;
      f32x4 f1 = *(const f32x4*)(src + 4);
      v[0] = f2s(f0[0]); v[1] = f2s(f0[1]); v[2] = f2s(f0[2]); v[3] = f2s(f0[3]);
      v[4] = f2s(f1[0]); v[5] = f2s(f1[1]); v[6] = f2s(f1[2]); v[7] = f2s(f1[3]);
      if (row >= 16) {                 // t in [t0, t0+64): x_skip passthrough
        float* dst = out1 + ((size_t)(b * 256 + t)) * 128 + col;
        *(f32x4*)dst = f0;
        *(f32x4*)(dst + 4) = f1;
      }
    }
    *(bf16x8*)(&AL[row][col]) = v;
  }
  __syncthreads();
  // ---- xc GEMM: wave w -> cols w*64..w*64+63, M=80 (bf16 W from ipwb) ----
  {
    f32x4 acc[5][4] = {};
#pragma unroll
    for (int ks = 0; ks < 4; ++ks) {
      const int k0 = ks * 32;
      bf16x8 wf[4];
#pragma unroll
      for (int j = 0; j < 4; ++j)
        wf[j] = *(const bf16x8*)(ipwb +
                 (size_t)(w * 64 + j * 16 + r16) * 128 + quad * 8 + k0);
#pragma unroll
      for (int mt = 0; mt < 5; ++mt) {
        bf16x8 a = *(const bf16x8*)(&AL[mt * 16 + r16][quad * 8 + k0]);
#pragma unroll
        for (int j = 0; j < 4; ++j)
          acc[mt][j] = __builtin_amdgcn_mfma_f32_16x16x32_bf16(a, wf[j],
                                                               acc[mt][j], 0, 0, 0);
      }
    }
#pragma unroll
    for (int mt = 0; mt < 5; ++mt)
#pragma unroll
      for (int j = 0; j < 4; ++j)
#pragma unroll
        for (int r = 0; r < 4; ++r)
          XC[mt * 16 + quad * 4 + r][w * 64 + j * 16 + r16] = f2s(acc[mt][j][r]);
  }
  // ---- z GEMM + silu -> zP packed (LT transpose per nt) ----
  for (int nt = 0; nt < 4; ++nt) {
    f32x4 accz[4] = {};
#pragma unroll
    for (int ks = 0; ks < 4; ++ks) {
      const int k0 = ks * 32;
      bf16x8 a = *(const bf16x8*)(&AL[16 + w * 16 + r16][quad * 8 + k0]);
#pragma unroll
      for (int j = 0; j < 4; ++j) {
        bf16x8 wf = *(const bf16x8*)(ipwb +
                 (size_t)(256 + nt * 64 + j * 16 + r16) * 128 + quad * 8 + k0);
        accz[j] = __builtin_amdgcn_mfma_f32_16x16x32_bf16(a, wf, accz[j], 0, 0, 0);
      }
    }
    __syncthreads();                    // prior LT reads done (and XC epilogue)
#pragma unroll
    for (int j = 0; j < 4; ++j)
#pragma unroll
      for (int r = 0; r < 4; ++r) {
        float v = accz[j][r];
        LT[j * 16 + r16][w * 16 + quad * 4 + r] = f2s(v / (1.f + __expf(-v)));
      }
    __syncthreads();
#pragma unroll
    for (int it = 0; it < 2; ++it) {
      const int dw = (threadIdx.x >> 3) + it * 32;
      const int tc = (threadIdx.x & 7) * 8;
      bf16x8 v = *(const bf16x8*)(&LT[dw][tc]);
      *(bf16x8*)(zP + pidx(b, nt * 64 + dw, t0 + tc)) = v;
    }
  }
  __syncthreads();
  // ---- conv + silu: thread (wave=16t, lane=d) x 4 dtiles ----
  bf16x8 cv[4][2];
#pragma unroll
  for (int dt_ = 0; dt_ < 4; ++dt_) {
    const int d = dt_ * 64 + lane;
    const float w0 = cw[d * 4], w1 = cw[d * 4 + 1];
    const float w2 = cw[d * 4 + 2], w3 = cw[d * 4 + 3];
    const float bias = cb[d];
    const int rb_ = 16 + w * 16;        // XC row of first output t
    float p0 = s2f(XC[rb_ - 3][d]);
    float p1 = s2f(XC[rb_ - 2][d]);
    float p2 = s2f(XC[rb_ - 1][d]);
#pragma unroll
    for (int i = 0; i < 16; ++i) {
      const float cur = s2f(XC[rb_ + i][d]);
      const float a = bias + p0 * w0 + p1 * w1 + p2 * w2 + cur * w3;
      const short s = f2s(a / (1.f + __expf(-a)));
      cv[dt_][i >> 3][i & 7] = s;
      p0 = p1; p1 = p2; p2 = cur;
    }
    *(bf16x8*)(xcP + pidx(b, d, t0 + w * 16))     = cv[dt_][0];
    *(bf16x8*)(xcP + pidx(b, d, t0 + w * 16 + 8)) = cv[dt_][1];
  }
  __syncthreads();
#pragma unroll
  for (int dt_ = 0; dt_ < 4; ++dt_) {
    const int d = dt_ * 64 + lane;
#pragma unroll
    for (int i = 0; i < 16; ++i)
      XC[16 + w * 16 + i][d] = cv[dt_][i >> 3][i & 7];
  }
  __syncthreads();
  // ---- x_proj MFMA: wave w = m-tile w (16 t), N=48 (40 used), K=256 ----
  // wxb rows 40..63 are zero, so plain loads for j=0..2; j=3 tile all-zero
  // and skipped.
  {
    f32x4 ax[3] = {};
#pragma unroll
    for (int ks = 0; ks < 8; ++ks) {
      const int k0 = ks * 32;
      bf16x8 a = *(const bf16x8*)(&XC[16 + w * 16 + r16][quad * 8 + k0]);
#pragma unroll
      for (int j = 0; j < 3; ++j) {
        bf16x8 wf = *(const bf16x8*)(wxb + (size_t)(j * 16 + r16) * 256 + quad * 8 + k0);
        ax[j] = __builtin_amdgcn_mfma_f32_16x16x32_bf16(a, wf, ax[j], 0, 0, 0);
      }
    }
#pragma unroll
    for (int j = 0; j < 3; ++j) {
      const int col = j * 16 + r16;
#pragma unroll
      for (int r = 0; r < 4; ++r) {
        const int tl = w * 16 + quad * 4 + r;
        if (col < 8) {
          DTL[tl][col] = ax[j][r];
        } else if (col < 40) {
          SBC[((size_t)b * 256 + t0 + tl) * 32 + (col - 8)] = ax[j][r];
        }
      }
    }
  }
  __syncthreads();
  // ---- delta = softplus(dt . dtw + dtb) -> dP packed ----
#pragma unroll
  for (int dt_ = 0; dt_ < 4; ++dt_) {
    const int d = dt_ * 64 + lane;
    float wd[8];
#pragma unroll
    for (int j = 0; j < 8; ++j) wd[j] = dtw[d * 8 + j];
    const float bd = dtb[d];
    bf16x8 dv0, dv1;
#pragma unroll
    for (int i = 0; i < 16; ++i) {
      const int tl = w * 16 + i;
      const f32x4 p0 = *(const f32x4*)(&DTL[tl][0]);
      const f32x4 p1 = *(const f32x4*)(&DTL[tl][4]);
      float acc = bd;
#pragma unroll
      for (int j = 0; j < 4; ++j) acc += p0[j] * wd[j] + p1[j] * wd[4 + j];
      const float delta = (acc > 20.f) ? acc : __logf(1.f + __expf(acc));
      const short s = f2s(delta);
      if (i < 8) dv0[i] = s; else dv1[i - 8] = s;
    }
    *(bf16x8*)(dP + pidx(b, d, t0 + w * 16))     = dv0;
    *(bf16x8*)(dP + pidx(b, d, t0 + w * 16 + 8)) = dv1;
  }
}

// ---------------------------------------------------------------------------
// scan12 (FROZEN scan; + G-prep rider blocks): blocks < 1024 run the R8
// skeleton + packed u/d/z scan. Blocks 1024..1791 compute
// G_k[co,e] = sum_dm dwn[co,dm,k]*opw[dm,e] (consumed by od_k, the NEXT
// stream-ordered launch -- no in-kernel ordering needed).
// ---------------------------------------------------------------------------
#define LDS_S(SB, CH) do {                                                   \
    _Pragma("unroll")                                                        \
    for (int j_ = 0; j_ < 8; ++j_) {                                         \
      SBr[SB][j_] = *(const f32x4*)(&S[(CH) * 8 + j_][q * 4]);               \
      SCr[SB][j_] = *(const f32x4*)(&S[(CH) * 8 + j_][16 + q * 4]);          \
    }                                                                        \
  } while (0)

#define LDG(GB, CH) do {                                                     \
    if ((CH) < 32) {                                                         \
      uu[GB] = *(const bf16x8*)(xcP + pb + (size_t)(CH) * 256);              \
      dd[GB] = *(const bf16x8*)(dP + pb + (size_t)(CH) * 256);               \
      if (q == 0) zz[GB] = *(const bf16x8*)(zP + pb + (size_t)(CH) * 256);   \
    }                                                                        \
  } while (0)

#define CHUNK(GB, SB, CH) do {                                               \
    _Pragma("unroll")                                                        \
    for (int tt_ = 0; tt_ < 8; ++tt_) {                                      \
      const int t_ = (CH) * 8 + tt_;                                         \
      const float delta_ = s2f(dd[GB][tt_]);                                 \
      const float u_ = s2f(uu[GB][tt_]);                                     \
      const float du_ = delta_ * u_;                                         \
      const f32x4 Bq_ = SBr[SB][tt_];                                        \
      const f32x4 Cq_ = SCr[SB][tt_];                                        \
      float yt_ = 0.f;                                                       \
      _Pragma("unroll")                                                      \
      for (int n_ = 0; n_ < 4; ++n_) {                                       \
        const float dA_ = __builtin_amdgcn_exp2f(delta_ * A2[n_]);           \
        h[n_] = dA_ * h[n_] + du_ * Bq_[n_];                                 \
        yt_ += h[n_] * Cq_[n_];                                              \
      }                                                                      \
      yt_ += __shfl_xor(yt_, 1);                                             \
      yt_ += __shfl_xor(yt_, 2);                                             \
      if (q == 0)                                                            \
        yb[(rb + t_) * 256 + d] = f2s((yt_ + u_ * Dv) * s2f(zz[GB][tt_]));   \
    }                                                                        \
  } while (0)

__global__ __launch_bounds__(128, 2) void scan12(const float* __restrict__ SBC,
                                                 const short* __restrict__ xcP,
                                                 const short* __restrict__ dP,
                                                 const short* __restrict__ zP,
                                                 const float* __restrict__ alog,
                                                 const float* __restrict__ Dp,
                                                 const float* __restrict__ dwn,
                                                 const float* __restrict__ opw,
                                                 short* __restrict__ G,
                                                 short* __restrict__ yb) {
  if (blockIdx.x >= 1024) {
    // ---- G-prep rider: jb in [0,768); k=jb/256, co=(jb%256)>>1,
    //      e = (jb&1)*128 + tid ----
    const int jb  = blockIdx.x - 1024;
    const int k   = jb >> 8;
    const int rem = jb & 255;
    const int co  = rem >> 1;
    const int e   = (rem & 1) * 128 + threadIdx.x;
    float acc = 0.f;
#pragma unroll 4
    for (int dm = 0; dm < 128; ++dm) {
      acc += dwn[(co * 128 + dm) * 3 + k] * opw[dm * 256 + e];
    }
    G[(size_t)(k * 128 + co) * 256 + e] = f2s(acc);
    return;
  }
  const int g = blockIdx.x & 7;
  const int b = blockIdx.x >> 3;
  const int q = threadIdx.x & 3;
  const int dl = threadIdx.x >> 2;            // 0..31 within group
  const int d = g * 32 + dl;
  const size_t rb = (size_t)b * 256;
  __shared__ float S[256][32];                // B(16)|C(16) fp32 per t, 32 KB
  for (int i = threadIdx.x; i < 2048; i += 128) {
    *(f32x4*)(&S[i >> 3][(i & 7) * 4]) =
        *(const f32x4*)(SBC + (size_t)b * 8192 + i * 4);
  }
  float A2[4];
#pragma unroll
  for (int n = 0; n < 4; ++n)
    A2[n] = -__expf(alog[d * 16 + q * 4 + n]) * 1.44269504089f;
  const float Dv = Dp[d];
  float h[4] = {0.f, 0.f, 0.f, 0.f};
  // packed per-lane base: [b][g][c=0][dl][0]
  const size_t pb = (((size_t)b * 8 + g) * 32) * 256 + (size_t)dl * 8;
  f32x4 SBr[2][8], SCr[2][8];
  bf16x8 uu[4], dd[4];
  bf16x8 zz[4] = {};
  // 4-deep global prologue (issues before the LDS-fill barrier)
  LDG(0, 0); LDG(1, 1); LDG(2, 2); LDG(3, 3);
  __syncthreads();
  LDS_S(0, 0);
  for (int c = 0; c < 32; c += 4) {
    LDS_S(1, c + 1);
    CHUNK(0, 0, c);
    LDG(0, c + 4);
    LDS_S(0, c + 2);
    CHUNK(1, 1, c + 1);
    LDG(1, c + 5);
    LDS_S(1, c + 3);
    CHUNK(2, 0, c + 2);
    LDG(2, c + 6);
    if (c + 4 < 32) LDS_S(0, c + 4);
    CHUNK(3, 1, c + 3);
    LDG(3, c + 7);
  }
}

// ---------------------------------------------------------------------------
// od_k (R8 form): fused out_proj + strided down-conv + bias + LayerNorm.
//   pre[b,to,co] = sum_k yb[b,2to+k-1,:] . G_k[co,:] + db[co]; out = LN(pre).
// Grid 256 x 256 thr (4 waves x 16 m-rows); K=768 via 3 row-shifted K=256
// segments; G L2-resident; LN via 16-lane shfl_xor.
// ---------------------------------------------------------------------------
__global__ __launch_bounds__(256) void od_k(const short* __restrict__ yb,
                                            const short* __restrict__ G,
                                            const float* __restrict__ db,
                                            const float* __restrict__ lng,
                                            const float* __restrict__ lnb,
                                            float* __restrict__ out) {
  const int wave = threadIdx.x >> 6;
  const int lane = threadIdx.x & 63;
  const int r16  = lane & 15;
  const int quad = lane >> 4;
  const int m_base = blockIdx.x * 64 + wave * 16;
  const int ma = m_base + r16;
  const int ba = ma >> 7, toa = ma & 127;
  f32x4 acc[8] = {};
  const bf16x8 az = {};
#pragma unroll
  for (int k = 0; k < 3; ++k) {
    const int tp = 2 * toa + k - 1;
    const bool valid = (tp >= 0) && (tp < 256);
    const int tpc = tp < 0 ? 0 : (tp > 255 ? 255 : tp);
    const short* Ap = yb + (size_t)(ba * 256 + tpc) * 256 + quad * 8;
    const short* Gp = G + (size_t)(k * 128 + r16) * 256 + quad * 8;
#pragma unroll
    for (int k0 = 0; k0 < 256; k0 += 32) {
      bf16x8 a = *(const bf16x8*)(Ap + k0);
      a = valid ? a : az;
#pragma unroll
      for (int j = 0; j < 8; ++j) {
        bf16x8 g = *(const bf16x8*)(Gp + (size_t)j * 16 * 256 + k0);
        acc[j] = __builtin_amdgcn_mfma_f32_16x16x32_bf16(a, g, acc[j], 0, 0, 0);
      }
    }
  }
  float dbv[8], g8[8], be8[8];
#pragma unroll
  for (int j = 0; j < 8; ++j) {
    const int col = j * 16 + r16;
    dbv[j] = db[col]; g8[j] = lng[col]; be8[j] = lnb[col];
  }
#pragma unroll
  for (int r = 0; r < 4; ++r) {
    float v[8];
    float s = 0.f;
#pragma unroll
    for (int j = 0; j < 8; ++j) { v[j] = acc[j][r] + dbv[j]; s += v[j]; }
    s += __shfl_xor(s, 1); s += __shfl_xor(s, 2);
    s += __shfl_xor(s, 4); s += __shfl_xor(s, 8);
    const float mu = s * (1.0f / 128.0f);
    float vs = 0.f;
#pragma unroll
    for (int j = 0; j < 8; ++j) { const float dd = v[j] - mu; vs += dd * dd; }
    vs += __shfl_xor(vs, 1); vs += __shfl_xor(vs, 2);
    vs += __shfl_xor(vs, 4); vs += __shfl_xor(vs, 8);
    const float rstd = rsqrtf(vs * (1.0f / 128.0f) + 1e-5f);
    const int rowm = m_base + quad * 4 + r;
#pragma unroll
    for (int j = 0; j < 8; ++j) {
      out[(size_t)rowm * 128 + j * 16 + r16] = (v[j] - mu) * rstd * g8[j] + be8[j];
    }
  }
}

// ---------------------------------------------------------------------------
// Workspace layout (bytes), peak 92,471,296 == proven-safe bound:
//   [0,16M)      yb bf16 (scan->od_k)
//   [16M,32M)    xcP bf16 packed (front_k->scan)
//   [32M,48M)    zP bf16 packed (front_k->scan)
//   [48M,64M)    dP bf16 packed (front_k->scan)
//   [64M,68.2M)  SBC fp32 4MB (front_k->scan)
//   [68.2M..71.5M) G bf16 196,608B (scan12 rider blocks -> od_k)
//   [88M,88.1M)  ipwb bf16 131,072B (prep_w->front_k)
// wxb staged in out0 (od_k overwrites out0 LAST); out1 written by front_k.
// ---------------------------------------------------------------------------
static const size_t O_YB    = 0;
static const size_t O_XCP   = 16777216;
static const size_t O_ZP    = 33554432;
static const size_t O_DP    = 50331648;
static const size_t O_SBC   = 67108864;     // 4,194,304 B
static const size_t O_G     = 71303168;     // 196,608 B
static const size_t O_IPWB  = 92274688;     // 131,072 B -> end 92,405,760

extern "C" void kernel_launch(void* const* d_in, const int* in_sizes, int n_in,
                              void* d_out, int out_size, void* d_ws, size_t ws_size,
                              hipStream_t stream) {
  const float* x    = (const float*)d_in[0];
  const float* ipw  = (const float*)d_in[1];
  const float* cw   = (const float*)d_in[2];
  const float* cb   = (const float*)d_in[3];
  const float* xpw  = (const float*)d_in[4];
  const float* dtw  = (const float*)d_in[5];
  const float* dtb  = (const float*)d_in[6];
  const float* alog = (const float*)d_in[7];
  const float* Dp   = (const float*)d_in[8];
  const float* opw  = (const float*)d_in[9];
  const float* dw   = (const float*)d_in[10];
  const float* db   = (const float*)d_in[11];
  const float* lng  = (const float*)d_in[12];
  const float* lnb  = (const float*)d_in[13];

  char*  ws     = (char*)d_ws;
  short* yb     = (short*)(ws + O_YB);
  short* xcP    = (short*)(ws + O_XCP);
  short* zP     = (short*)(ws + O_ZP);
  short* dP     = (short*)(ws + O_DP);
  float* SBC    = (float*)(ws + O_SBC);
  short* G      = (short*)(ws + O_G);
  short* ipwb   = (short*)(ws + O_IPWB);
  float* out    = (float*)d_out;
  short* wxb    = (short*)out;             // out0 staging; od_k writes last
  float* out1   = out + 2097152;

  // 0. tiny weight prep: ipw/xpw -> bf16
  prep_w<<<320, 256, 0, stream>>>(ipw, xpw, ipwb, wxb);
  // 1. fused in_proj + conv/silu + x_proj + delta (+ out1 x_skip)
  front_k<<<512, 256, 0, stream>>>(x, ipwb, wxb, cw, cb, dtw, dtb,
                                   xcP, dP, zP, SBC, out1);
  // 2. state-parallel scan (FROZEN) + G-prep rider blocks -> yb, G
  scan12<<<1792, 128, 0, stream>>>(SBC, xcP, dP, zP, alog, Dp, dw, opw, G, yb);
  // 3. fused out_proj + down-conv + bias + LayerNorm -> output 0
  od_k<<<256, 256, 0, stream>>>(yb, G, db, lng, lnb, out);
}